// Round 5
// baseline (238.427 us; speedup 1.0000x reference)
//
#include <hip/hip_runtime.h>
#include <hip/hip_bf16.h>

#define B_N 8192
#define D_K 256
#define MARGIN 0.3f
#define NTILE 2080   // 64*65/2 triangular tiles

typedef float f32x4 __attribute__((ext_vector_type(4)));
typedef short s16x8 __attribute__((ext_vector_type(8)));

// Order-preserving float->uint for atomicMax/atomicMin on floats.
__device__ __forceinline__ unsigned fkey(float f) {
    unsigned u = __float_as_uint(f);
    return (u & 0x80000000u) ? ~u : (u | 0x80000000u);
}
__device__ __forceinline__ float kval(unsigned k) {
    return (k & 0x80000000u) ? __uint_as_float(k ^ 0x80000000u)
                             : __uint_as_float(~k);
}

// async 16B global -> LDS (LDS dest = wave-uniform base + lane*16)
__device__ __forceinline__ void load_lds16(const unsigned short* g,
                                           unsigned short* l) {
    __builtin_amdgcn_global_load_lds(
        (const __attribute__((address_space(1))) unsigned int*)g,
        (__attribute__((address_space(3))) unsigned int*)l, 16, 0, 0);
}

// ---- kernel 1: bf16 round + norms OF ROUNDED VALUES + init ----------------
__global__ __launch_bounds__(256) void prep_kernel(const float* __restrict__ X,
        float* __restrict__ sq, unsigned* __restrict__ apk,
        unsigned* __restrict__ ank, unsigned short* __restrict__ Xp,
        float* __restrict__ acc2) {
    int row  = (blockIdx.x << 2) + (threadIdx.x >> 6);
    int lane = threadIdx.x & 63;
    const float4 v = reinterpret_cast<const float4*>(X + (size_t)row * D_K)[lane];

    float xs[4] = {v.x, v.y, v.z, v.w};
    ushort4 hv;
    unsigned short* hp = &hv.x;
    float s = 0.f;
    #pragma unroll
    for (int i = 0; i < 4; ++i) {
        __hip_bfloat16 h = __float2bfloat16(xs[i]);
        hp[i] = *reinterpret_cast<unsigned short*>(&h);
        float hf = __bfloat162float(h);
        s = fmaf(hf, hf, s);
    }
    *reinterpret_cast<ushort4*>(Xp + (size_t)row * D_K + lane * 4) = hv;

    #pragma unroll
    for (int o = 32; o > 0; o >>= 1) s += __shfl_down(s, o, 64);
    if (lane == 0) {
        sq[row]  = s;
        apk[row] = 0u;           // <= fkey(-inf)
        ank[row] = 0xFFFFFFFFu;  // >= fkey(+inf)
    }
    if (blockIdx.x == 0 && threadIdx.x == 0) {
        reinterpret_cast<unsigned*>(acc2)[2] = 0u;   // ticket counter
    }
}

// ---- kernel 2: R0 structure (proven 57.6us) + LDS row-mining + fused final -
#define BM 128
#define BN 128
// K-loop identical to the verified round-0 kernel: 32 KB tiles, 2-phase per
// 64-k window, global_load_lds staging with pre-swizzled source (u^(r&7)).
// Epilogue: row partials scattered to a [128][33] f32 scratch (overlaid on
// the dead tiles), reduced by 256 threads with plain LDS reads -- replaces
// 128 serial shuffle ops/thread. Col mining unchanged (16 shuffles).
// Finalize fused via device ticket: last block coherently re-reads apk/ank
// (atomicOr(p,0) -- plain loads could hit a stale per-XCD L2 line) and
// writes loss/prec. Deletes final_kernel's launch.

__global__ __launch_bounds__(256, 4) void dist_kernel(
        const unsigned short* __restrict__ Xp,
        const int* __restrict__ tgt, const float* __restrict__ sq,
        unsigned* __restrict__ apk, unsigned* __restrict__ ank,
        unsigned* __restrict__ tick, float* __restrict__ out) {
    // union: tiles = 2 x 128x64 ushort (32 KB) ; mine = 2 x [128][33] f32
    __shared__ __align__(16) float smem_f[2 * 128 * 33];   // 33792 B
    __shared__ unsigned lastflag;
    unsigned short* Atile = reinterpret_cast<unsigned short*>(smem_f);
    unsigned short* Btile = Atile + 128 * 64;

    const int t    = threadIdx.x;
    const int lane = t & 63;
    const int wave = t >> 6;
    const int wrow = (wave >> 1) * 64;
    const int wcol = (wave & 1) * 64;
    const int fr   = lane & 15;
    const int quad = lane >> 4;
    const float INF = __int_as_float(0x7f800000);

    // triangular decode: blockIdx.x -> (bx, by), by <= bx
    int tt = blockIdx.x;
    int bx = (int)((sqrtf(8.f * (float)tt + 1.f) - 1.f) * 0.5f);
    while ((bx + 1) * (bx + 2) / 2 <= tt) ++bx;
    while (bx * (bx + 1) / 2 > tt) --bx;
    int by = tt - bx * (bx + 1) / 2;
    const int bm = by * BM;   // bm <= bn
    const int bn = bx * BN;

    // staging geometry: thread's 4 units per operand
    const unsigned short* ag[4];
    const unsigned short* bg[4];
    unsigned short* al[4];
    unsigned short* bl[4];
    #pragma unroll
    for (int j = 0; j < 4; ++j) {
        int g = wave * 64 + j * 256 + lane;   // 0..1023
        int r = g >> 3, s0 = g & 7;
        int u = s0 ^ (r & 7);
        ag[j] = Xp + (size_t)(bm + r) * D_K + u * 8;
        bg[j] = Xp + (size_t)(bn + r) * D_K + u * 8;
        al[j] = Atile + g * 8;                // wave base + lane*16B
        bl[j] = Btile + g * 8;
    }

    f32x4 acc[4][4];
    #pragma unroll
    for (int i = 0; i < 4; ++i)
        #pragma unroll
        for (int j = 0; j < 4; ++j) acc[i][j] = (f32x4){0.f, 0.f, 0.f, 0.f};

    #pragma unroll 1
    for (int win = 0; win < 4; ++win) {   // K = 64 per window
        __syncthreads();                  // prior fragment reads complete
        const int wo = win * 64;
        #pragma unroll
        for (int j = 0; j < 4; ++j) {
            load_lds16(ag[j] + wo, al[j]);
            load_lds16(bg[j] + wo, bl[j]);
        }
        __syncthreads();                  // staging drained

        s16x8 a[4][2], b[4][2];
        #pragma unroll
        for (int mi = 0; mi < 4; ++mi) {
            int rb = (wrow + mi * 16 + fr) * 64;
            #pragma unroll
            for (int h = 0; h < 2; ++h) {
                int s = (h * 4 + quad) ^ (fr & 7);
                a[mi][h] = *reinterpret_cast<const s16x8*>(&Atile[rb + s * 8]);
            }
        }
        #pragma unroll
        for (int ni = 0; ni < 4; ++ni) {
            int rb = (wcol + ni * 16 + fr) * 64;
            #pragma unroll
            for (int h = 0; h < 2; ++h) {
                int s = (h * 4 + quad) ^ (fr & 7);
                b[ni][h] = *reinterpret_cast<const s16x8*>(&Btile[rb + s * 8]);
            }
        }
        #pragma unroll
        for (int mi = 0; mi < 4; ++mi)
            #pragma unroll
            for (int ni = 0; ni < 4; ++ni) {
                acc[mi][ni] = __builtin_amdgcn_mfma_f32_16x16x32_bf16(
                    a[mi][0], b[ni][0], acc[mi][ni], 0, 0, 0);
                acc[mi][ni] = __builtin_amdgcn_mfma_f32_16x16x32_bf16(
                    a[mi][1], b[ni][1], acc[mi][ni], 0, 0, 0);
            }
    }

    // -------- epilogue --------------------------------------------------
    __syncthreads();   // all tile reads done -> smem reusable as mine scratch

    int   ct[4]; float csq[4];
    #pragma unroll
    for (int ni = 0; ni < 4; ++ni) {
        int c = bn + wcol + ni * 16 + fr;
        ct[ni] = tgt[c]; csq[ni] = sq[c];
    }
    float cap[4], can[4];
    #pragma unroll
    for (int ni = 0; ni < 4; ++ni) { cap[ni] = -INF; can[ni] = INF; }

    const int mcol = (wave & 1) * 16 + fr;   // 0..31 partial slot
    #pragma unroll
    for (int mi = 0; mi < 4; ++mi) {
        #pragma unroll
        for (int reg = 0; reg < 4; ++reg) {
            int rl = wrow + mi * 16 + quad * 4 + reg;   // 0..127
            int rt = tgt[bm + rl]; float rsq = sq[bm + rl];
            float rap = -INF, ran = INF;
            #pragma unroll
            for (int ni = 0; ni < 4; ++ni) {
                float d = rsq + csq[ni] - 2.f * acc[mi][ni][reg];
                bool pos = (rt == ct[ni]);
                if (pos) { rap = fmaxf(rap, d); cap[ni] = fmaxf(cap[ni], d); }
                else     { ran = fminf(ran, d); can[ni] = fminf(can[ni], d); }
            }
            smem_f[rl * 33 + mcol]        = rap;   // AP partials
            smem_f[4224 + rl * 33 + mcol] = ran;   // AN partials
        }
    }

    // col mining: reduce across quad groups (cheap: 16 shuffle ops)
    #pragma unroll
    for (int ni = 0; ni < 4; ++ni) {
        #pragma unroll
        for (int o = 16; o < 64; o <<= 1) {
            cap[ni] = fmaxf(cap[ni], __shfl_xor(cap[ni], o, 64));
            can[ni] = fminf(can[ni], __shfl_xor(can[ni], o, 64));
        }
    }
    if (lane < 16) {
        #pragma unroll
        for (int ni = 0; ni < 4; ++ni) {
            int c = bn + wcol + ni * 16 + lane;
            atomicMax(&apk[c], fkey(cap[ni]));
            atomicMin(&ank[c], fkey(can[ni]));
        }
    }

    __syncthreads();   // all partials written
    // row mining: 256 threads, one (row, array) each; no cross-lane ops
    {
        int arr = t >> 7;        // 0 = AP(max), 1 = AN(min)
        int row = t & 127;
        const float* p = smem_f + arr * 4224 + row * 33;
        float v = p[0];
        if (arr == 0) {
            #pragma unroll
            for (int j = 1; j < 32; ++j) v = fmaxf(v, p[j]);
            atomicMax(&apk[bm + row], fkey(v));
        } else {
            #pragma unroll
            for (int j = 1; j < 32; ++j) v = fminf(v, p[j]);
            atomicMin(&ank[bm + row], fkey(v));
        }
    }

    // -------- fused finalize via ticket ---------------------------------
    __threadfence();       // release this block's atomics device-wide
    __syncthreads();
    if (t == 0) lastflag = (atomicAdd(tick, 1u) == NTILE - 1u) ? 1u : 0u;
    __syncthreads();
    if (lastflag) {
        __threadfence();   // acquire
        float sum = 0.f, cnt = 0.f;
        for (int i = t; i < B_N; i += 256) {
            float ap = kval(atomicOr(&apk[i], 0u));   // coherent read
            float an = kval(atomicOr(&ank[i], 0u));
            float v  = ap - an + MARGIN;
            sum += v > 0.f ? v : 0.f;
            cnt += an > ap ? 1.f : 0.f;
        }
        #pragma unroll
        for (int o = 32; o > 0; o >>= 1) {
            sum += __shfl_down(sum, o, 64);
            cnt += __shfl_down(cnt, o, 64);
        }
        if (lane == 0) { smem_f[wave] = sum; smem_f[8 + wave] = cnt; }
        __syncthreads();
        if (t == 0) {
            float ts = 0.f, tc = 0.f;
            #pragma unroll
            for (int w = 0; w < 4; ++w) { ts += smem_f[w]; tc += smem_f[8 + w]; }
            out[0] = ts / (float)B_N;
            out[1] = tc / (float)B_N;
        }
    }
}

extern "C" void kernel_launch(void* const* d_in, const int* in_sizes, int n_in,
                              void* d_out, int out_size, void* d_ws, size_t ws_size,
                              hipStream_t stream) {
    const float* X   = (const float*)d_in[0];
    const int*   tgt = (const int*)d_in[1];

    char* ws = (char*)d_ws;
    float*          sq   = (float*)ws;                    // 32 KB
    unsigned*       apk  = (unsigned*)(ws + 32768);       // 32 KB
    unsigned*       ank  = (unsigned*)(ws + 65536);       // 32 KB
    float*          acc2 = (float*)(ws + 98304);          // 12 B
    unsigned short* Xp   = (unsigned short*)(ws + 131072);// 4 MB

    unsigned* tick = reinterpret_cast<unsigned*>(acc2) + 2;
    float* out = (float*)d_out;

    prep_kernel<<<B_N / 4, 256, 0, stream>>>(X, sq, apk, ank, Xp, acc2);
    dist_kernel<<<NTILE, 256, 0, stream>>>(Xp, tgt, sq, apk, ank, tick, out);
}

// Round 6
// 123.932 us; speedup vs baseline: 1.9238x; 1.9238x over previous
//
#include <hip/hip_runtime.h>
#include <hip/hip_bf16.h>

#define B_N 8192
#define D_K 256
#define MARGIN 0.3f

typedef float f32x4 __attribute__((ext_vector_type(4)));
typedef short s16x8 __attribute__((ext_vector_type(8)));

// Order-preserving float->uint for atomicMax/atomicMin on floats.
__device__ __forceinline__ unsigned fkey(float f) {
    unsigned u = __float_as_uint(f);
    return (u & 0x80000000u) ? ~u : (u | 0x80000000u);
}
__device__ __forceinline__ float kval(unsigned k) {
    return (k & 0x80000000u) ? __uint_as_float(k ^ 0x80000000u)
                             : __uint_as_float(~k);
}

// async 16B global -> LDS (LDS dest = wave-uniform base + lane*16)
__device__ __forceinline__ void load_lds16(const unsigned short* g,
                                           unsigned short* l) {
    __builtin_amdgcn_global_load_lds(
        (const __attribute__((address_space(1))) unsigned int*)g,
        (__attribute__((address_space(3))) unsigned int*)l, 16, 0, 0);
}

// ---- kernel 1: bf16 round + norms OF ROUNDED VALUES + init ----------------
__global__ __launch_bounds__(256) void prep_kernel(const float* __restrict__ X,
        float* __restrict__ sq, unsigned* __restrict__ apk,
        unsigned* __restrict__ ank, unsigned short* __restrict__ Xp,
        float* __restrict__ acc2) {
    int row  = (blockIdx.x << 2) + (threadIdx.x >> 6);
    int lane = threadIdx.x & 63;
    const float4 v = reinterpret_cast<const float4*>(X + (size_t)row * D_K)[lane];

    float xs[4] = {v.x, v.y, v.z, v.w};
    ushort4 hv;
    unsigned short* hp = &hv.x;
    float s = 0.f;
    #pragma unroll
    for (int i = 0; i < 4; ++i) {
        __hip_bfloat16 h = __float2bfloat16(xs[i]);
        hp[i] = *reinterpret_cast<unsigned short*>(&h);
        float hf = __bfloat162float(h);
        s = fmaf(hf, hf, s);
    }
    *reinterpret_cast<ushort4*>(Xp + (size_t)row * D_K + lane * 4) = hv;

    #pragma unroll
    for (int o = 32; o > 0; o >>= 1) s += __shfl_down(s, o, 64);
    if (lane == 0) {
        sq[row]  = s;
        apk[row] = 0u;           // <= fkey(-inf)
        ank[row] = 0xFFFFFFFFu;  // >= fkey(+inf)
    }
    if (blockIdx.x == 0 && threadIdx.x == 0) {
        acc2[0] = 0.f; acc2[1] = 0.f;
        reinterpret_cast<unsigned*>(acc2)[2] = 0u;   // ticket counter
    }
}

// ---- kernel 2: R0 structure, BK=32 double-buffer at SAME 32 KB LDS --------
#define BM 128
#define BN 128
#define NWIN 8    // 8 windows of K=32
// Per buffer per operand: 128 rows x 32 shorts (64 B rows, 4 x 16B units).
// Unit u of row r stored at slot u ^ f(r), f(r) = (r&3)^((r>>2)&3):
// pre-swizzled at the GLOBAL source (LDS linear for global_load_lds), read
// back with the same XOR -> <=2-way (free) bank aliasing on ds_read_b128.
// Schedule per window: __syncthreads (win staged + prior-buffer reads done)
// -> issue win+1 loads into other buffer -> ds_read + 16 MFMA. The prefetch
// has a full compute phase between issue and its vmcnt wait -> L2 latency
// hidden. Total LDS unchanged vs the proven 57.6us kernel (occupancy kept).

__global__ __launch_bounds__(256, 4) void dist_kernel(
        const unsigned short* __restrict__ Xp,
        const int* __restrict__ tgt, const float* __restrict__ sq,
        unsigned* __restrict__ apk, unsigned* __restrict__ ank) {
    __shared__ unsigned short Atile[2][128 * 32];   // 2 x 8 KB
    __shared__ unsigned short Btile[2][128 * 32];   // 2 x 8 KB

    const int t    = threadIdx.x;
    const int lane = t & 63;
    const int wave = t >> 6;
    const int wrow = (wave >> 1) * 64;
    const int wcol = (wave & 1) * 64;
    const int fr   = lane & 15;
    const int quad = lane >> 4;
    const float INF = __int_as_float(0x7f800000);

    // triangular decode: blockIdx.x -> (bx, by), by <= bx
    int tt = blockIdx.x;
    int bx = (int)((sqrtf(8.f * (float)tt + 1.f) - 1.f) * 0.5f);
    while ((bx + 1) * (bx + 2) / 2 <= tt) ++bx;
    while (bx * (bx + 1) / 2 > tt) --bx;
    int by = tt - bx * (bx + 1) / 2;
    const int bm = by * BM;   // bm <= bn
    const int bn = bx * BN;

    // staging geometry: 512 16B-units per operand per window; 2 per thread
    const unsigned short* ag[2];
    const unsigned short* bg[2];
    int loff[2];
    #pragma unroll
    for (int j = 0; j < 2; ++j) {
        int g = j * 256 + t;                 // 0..511
        int r = g >> 2, s0 = g & 3;
        int u = s0 ^ (r & 3) ^ ((r >> 2) & 3);
        ag[j] = Xp + (size_t)(bm + r) * D_K + u * 8;
        bg[j] = Xp + (size_t)(bn + r) * D_K + u * 8;
        loff[j] = g * 8;                     // wave-uniform base + lane*16B
    }

    // fragment read offsets (shorts, within one 8 KB tile)
    const int fswz = (fr & 3) ^ ((fr >> 2) & 3);
    int aoff[4], boff[4];
    #pragma unroll
    for (int i = 0; i < 4; ++i) {
        int s = quad ^ fswz;
        aoff[i] = (wrow + i * 16 + fr) * 32 + s * 8;
        boff[i] = (wcol + i * 16 + fr) * 32 + s * 8;
    }

    f32x4 acc[4][4];
    #pragma unroll
    for (int i = 0; i < 4; ++i)
        #pragma unroll
        for (int j = 0; j < 4; ++j) acc[i][j] = (f32x4){0.f, 0.f, 0.f, 0.f};

    // prologue: stage window 0 into buffer 0
    #pragma unroll
    for (int j = 0; j < 2; ++j) {
        load_lds16(ag[j], &Atile[0][loff[j]]);
        load_lds16(bg[j], &Btile[0][loff[j]]);
    }

    #pragma unroll
    for (int win = 0; win < NWIN; ++win) {
        // window `win` staged + visible; prior reads of other buffer done
        __syncthreads();
        if (win < NWIN - 1) {               // prefetch next window
            const int wo = (win + 1) * 32;
            const int nb = (win + 1) & 1;
            #pragma unroll
            for (int j = 0; j < 2; ++j) {
                load_lds16(ag[j] + wo, &Atile[nb][loff[j]]);
                load_lds16(bg[j] + wo, &Btile[nb][loff[j]]);
            }
        }
        const int cur = win & 1;
        s16x8 a[4], b[4];
        #pragma unroll
        for (int mi = 0; mi < 4; ++mi)
            a[mi] = *reinterpret_cast<const s16x8*>(&Atile[cur][aoff[mi]]);
        #pragma unroll
        for (int ni = 0; ni < 4; ++ni)
            b[ni] = *reinterpret_cast<const s16x8*>(&Btile[cur][boff[ni]]);
        #pragma unroll
        for (int mi = 0; mi < 4; ++mi)
            #pragma unroll
            for (int ni = 0; ni < 4; ++ni)
                acc[mi][ni] = __builtin_amdgcn_mfma_f32_16x16x32_bf16(
                    a[mi], b[ni], acc[mi][ni], 0, 0, 0);
    }

    // -------- epilogue: dist + row mining + col mining (verbatim R0) -------
    int   ct[4]; float csq[4];
    #pragma unroll
    for (int ni = 0; ni < 4; ++ni) {
        int c = bn + wcol + ni * 16 + fr;
        ct[ni] = tgt[c]; csq[ni] = sq[c];
    }
    float cap[4], can[4];
    #pragma unroll
    for (int ni = 0; ni < 4; ++ni) { cap[ni] = -INF; can[ni] = INF; }

    #pragma unroll
    for (int mi = 0; mi < 4; ++mi) {
        #pragma unroll
        for (int reg = 0; reg < 4; ++reg) {
            int rl = wrow + mi * 16 + quad * 4 + reg;
            int rt = tgt[bm + rl]; float rsq = sq[bm + rl];
            float rap = -INF, ran = INF;
            #pragma unroll
            for (int ni = 0; ni < 4; ++ni) {
                float d = rsq + csq[ni] - 2.f * acc[mi][ni][reg];
                bool pos = (rt == ct[ni]);
                if (pos) { rap = fmaxf(rap, d); cap[ni] = fmaxf(cap[ni], d); }
                else     { ran = fminf(ran, d); can[ni] = fminf(can[ni], d); }
            }
            #pragma unroll
            for (int o = 1; o < 16; o <<= 1) {
                rap = fmaxf(rap, __shfl_xor(rap, o, 64));
                ran = fminf(ran, __shfl_xor(ran, o, 64));
            }
            if (fr == 0) {
                atomicMax(&apk[bm + rl], fkey(rap));
                atomicMin(&ank[bm + rl], fkey(ran));
            }
        }
    }
    #pragma unroll
    for (int ni = 0; ni < 4; ++ni) {
        #pragma unroll
        for (int o = 16; o < 64; o <<= 1) {
            cap[ni] = fmaxf(cap[ni], __shfl_xor(cap[ni], o, 64));
            can[ni] = fminf(can[ni], __shfl_xor(can[ni], o, 64));
        }
    }
    if (lane < 16) {
        #pragma unroll
        for (int ni = 0; ni < 4; ++ni) {
            int c = bn + wcol + ni * 16 + lane;
            atomicMax(&apk[c], fkey(cap[ni]));
            atomicMin(&ank[c], fkey(can[ni]));
        }
    }
}

// ---- kernel 3: loss/prec partial sums + last-block finalize ---------------
__global__ __launch_bounds__(256) void final_kernel(const unsigned* __restrict__ apk,
        const unsigned* __restrict__ ank, float* __restrict__ acc2,
        float* __restrict__ out) {
    __shared__ float s_sum[4], s_cnt[4];
    int i = blockIdx.x * 256 + threadIdx.x;
    float ap = kval(apk[i]);
    float an = kval(ank[i]);
    float v  = ap - an + MARGIN;
    float sum = v > 0.f ? v : 0.f;
    float cnt = an > ap ? 1.f : 0.f;
    #pragma unroll
    for (int o = 32; o > 0; o >>= 1) {
        sum += __shfl_down(sum, o, 64);
        cnt += __shfl_down(cnt, o, 64);
    }
    int wave = threadIdx.x >> 6, lane = threadIdx.x & 63;
    if (lane == 0) { s_sum[wave] = sum; s_cnt[wave] = cnt; }
    __syncthreads();
    if (threadIdx.x == 0) {
        float ts = 0.f, tc = 0.f;
        #pragma unroll
        for (int w = 0; w < 4; ++w) { ts += s_sum[w]; tc += s_cnt[w]; }
        atomicAdd(&acc2[0], ts);
        atomicAdd(&acc2[1], tc);
        __threadfence();
        unsigned ticket = atomicAdd(reinterpret_cast<unsigned*>(acc2) + 2, 1u);
        if (ticket == gridDim.x - 1) {
            float fs = atomicAdd(&acc2[0], 0.f);
            float fc = atomicAdd(&acc2[1], 0.f);
            out[0] = fs / (float)B_N;
            out[1] = fc / (float)B_N;
        }
    }
}

extern "C" void kernel_launch(void* const* d_in, const int* in_sizes, int n_in,
                              void* d_out, int out_size, void* d_ws, size_t ws_size,
                              hipStream_t stream) {
    const float* X   = (const float*)d_in[0];
    const int*   tgt = (const int*)d_in[1];

    char* ws = (char*)d_ws;
    float*          sq   = (float*)ws;                    // 32 KB
    unsigned*       apk  = (unsigned*)(ws + 32768);       // 32 KB
    unsigned*       ank  = (unsigned*)(ws + 65536);       // 32 KB
    float*          acc2 = (float*)(ws + 98304);          // 12 B
    unsigned short* Xp   = (unsigned short*)(ws + 131072);// 4 MB

    float* out = (float*)d_out;

    prep_kernel<<<B_N / 4, 256, 0, stream>>>(X, sq, apk, ank, Xp, acc2);
    dist_kernel<<<(64 * 65) / 2, 256, 0, stream>>>(Xp, tgt, sq, apk, ank);
    final_kernel<<<B_N / 256, 256, 0, stream>>>(apk, ank, acc2, out);
}

// Round 8
// 120.894 us; speedup vs baseline: 1.9722x; 1.0251x over previous
//
#include <hip/hip_runtime.h>
#include <hip/hip_bf16.h>

#define B_N 8192
#define D_K 256
#define MARGIN 0.3f
#define NPAN 64     // 8192 / 128 panels

typedef float f32x4 __attribute__((ext_vector_type(4)));
typedef short s16x8 __attribute__((ext_vector_type(8)));

// async 16B global -> LDS (LDS dest = wave-uniform base + lane*16)
__device__ __forceinline__ void load_lds16(const unsigned short* g,
                                           unsigned short* l) {
    __builtin_amdgcn_global_load_lds(
        (const __attribute__((address_space(1))) unsigned int*)g,
        (__attribute__((address_space(3))) unsigned int*)l, 16, 0, 0);
}

// ---- kernel 1: bf16 round + norms OF ROUNDED VALUES + init ----------------
__global__ __launch_bounds__(256) void prep_kernel(const float* __restrict__ X,
        float* __restrict__ sq, unsigned short* __restrict__ Xp,
        float* __restrict__ acc2) {
    int row  = (blockIdx.x << 2) + (threadIdx.x >> 6);
    int lane = threadIdx.x & 63;
    const float4 v = reinterpret_cast<const float4*>(X + (size_t)row * D_K)[lane];

    float xs[4] = {v.x, v.y, v.z, v.w};
    ushort4 hv;
    unsigned short* hp = &hv.x;
    float s = 0.f;
    #pragma unroll
    for (int i = 0; i < 4; ++i) {
        __hip_bfloat16 h = __float2bfloat16(xs[i]);
        hp[i] = *reinterpret_cast<unsigned short*>(&h);
        float hf = __bfloat162float(h);
        s = fmaf(hf, hf, s);
    }
    *reinterpret_cast<ushort4*>(Xp + (size_t)row * D_K + lane * 4) = hv;

    #pragma unroll
    for (int o = 32; o > 0; o >>= 1) s += __shfl_down(s, o, 64);
    if (lane == 0) sq[row] = s;
    if (blockIdx.x == 0 && threadIdx.x == 0) {
        acc2[0] = 0.f; acc2[1] = 0.f;
        reinterpret_cast<unsigned*>(acc2)[2] = 0u;   // ticket counter
    }
}

// ---- kernel 2: R0 K-loop (proven) + ATOMIC-FREE mining --------------------
#define BM 128
#define BN 128
// K-loop verbatim from the 57.6us round-0 kernel (32 KB tiles, 2-phase per
// 64-k window, pre-swizzled global_load_lds, zero bank conflicts).
// Mining: wave-pair partials combined via a 2 KB LDS scratch (one barrier),
// then ONE plain f32 store per (slot,row): part[q][i] with
//   row side of block (bx,by): part[bx][bm+rl]   (waves 1,3 store)
//   col side of block (bx,by): part[by][bn+c]    (waves 2,3 store; skip diag)
// For row i in panel p: row-side fills slots p..63, col-side slots 0..p-1.
// Every (slot,row) has exactly ONE writer -> no atomics, no init, no races.
// (Diag col side == row side by symmetry of the distance tile.)

__global__ __launch_bounds__(256, 4) void dist_kernel(
        const unsigned short* __restrict__ Xp,
        const int* __restrict__ tgt, const float* __restrict__ sq,
        float* __restrict__ part_ap, float* __restrict__ part_an) {
    __shared__ unsigned short Atile[128 * 64];   // 16 KB
    __shared__ unsigned short Btile[128 * 64];   // 16 KB
    __shared__ float rowap[128], rowan[128], colap[128], colan[128]; // 2 KB

    const int t    = threadIdx.x;
    const int lane = t & 63;
    const int wave = t >> 6;
    const int wrow = (wave >> 1) * 64;
    const int wcol = (wave & 1) * 64;
    const int fr   = lane & 15;
    const int quad = lane >> 4;
    const float INF = __int_as_float(0x7f800000);

    // triangular decode: blockIdx.x -> (bx, by), by <= bx
    int tt = blockIdx.x;
    int bx = (int)((sqrtf(8.f * (float)tt + 1.f) - 1.f) * 0.5f);
    while ((bx + 1) * (bx + 2) / 2 <= tt) ++bx;
    while (bx * (bx + 1) / 2 > tt) --bx;
    int by = tt - bx * (bx + 1) / 2;
    const int bm = by * BM;   // bm <= bn
    const int bn = bx * BN;

    // staging geometry: thread's 4 units per operand
    const unsigned short* ag[4];
    const unsigned short* bg[4];
    unsigned short* al[4];
    unsigned short* bl[4];
    #pragma unroll
    for (int j = 0; j < 4; ++j) {
        int g = wave * 64 + j * 256 + lane;   // 0..1023
        int r = g >> 3, s0 = g & 7;
        int u = s0 ^ (r & 7);
        ag[j] = Xp + (size_t)(bm + r) * D_K + u * 8;
        bg[j] = Xp + (size_t)(bn + r) * D_K + u * 8;
        al[j] = Atile + g * 8;                // wave base + lane*16B
        bl[j] = Btile + g * 8;
    }

    f32x4 acc[4][4];
    #pragma unroll
    for (int i = 0; i < 4; ++i)
        #pragma unroll
        for (int j = 0; j < 4; ++j) acc[i][j] = (f32x4){0.f, 0.f, 0.f, 0.f};

    #pragma unroll 1
    for (int win = 0; win < 4; ++win) {   // K = 64 per window
        __syncthreads();                  // prior fragment reads complete
        const int wo = win * 64;
        #pragma unroll
        for (int j = 0; j < 4; ++j) {
            load_lds16(ag[j] + wo, al[j]);
            load_lds16(bg[j] + wo, bl[j]);
        }
        __syncthreads();                  // staging drained

        s16x8 a[4][2], b[4][2];
        #pragma unroll
        for (int mi = 0; mi < 4; ++mi) {
            int rb = (wrow + mi * 16 + fr) * 64;
            #pragma unroll
            for (int h = 0; h < 2; ++h) {
                int s = (h * 4 + quad) ^ (fr & 7);
                a[mi][h] = *reinterpret_cast<const s16x8*>(&Atile[rb + s * 8]);
            }
        }
        #pragma unroll
        for (int ni = 0; ni < 4; ++ni) {
            int rb = (wcol + ni * 16 + fr) * 64;
            #pragma unroll
            for (int h = 0; h < 2; ++h) {
                int s = (h * 4 + quad) ^ (fr & 7);
                b[ni][h] = *reinterpret_cast<const s16x8*>(&Btile[rb + s * 8]);
            }
        }
        #pragma unroll
        for (int mi = 0; mi < 4; ++mi)
            #pragma unroll
            for (int ni = 0; ni < 4; ++ni) {
                acc[mi][ni] = __builtin_amdgcn_mfma_f32_16x16x32_bf16(
                    a[mi][0], b[ni][0], acc[mi][ni], 0, 0, 0);
                acc[mi][ni] = __builtin_amdgcn_mfma_f32_16x16x32_bf16(
                    a[mi][1], b[ni][1], acc[mi][ni], 0, 0, 0);
            }
    }

    // -------- epilogue: dist + mining, NO ATOMICS --------------------------
    int   ct[4]; float csq[4];
    #pragma unroll
    for (int ni = 0; ni < 4; ++ni) {
        int c = bn + wcol + ni * 16 + fr;
        ct[ni] = tgt[c]; csq[ni] = sq[c];
    }
    float cap[4], can[4];
    #pragma unroll
    for (int ni = 0; ni < 4; ++ni) { cap[ni] = -INF; can[ni] = INF; }

    float rapv[16], ranv[16];
    #pragma unroll
    for (int mi = 0; mi < 4; ++mi) {
        #pragma unroll
        for (int reg = 0; reg < 4; ++reg) {
            int rl = wrow + mi * 16 + quad * 4 + reg;
            int rt = tgt[bm + rl]; float rsq = sq[bm + rl];
            float rap = -INF, ran = INF;
            #pragma unroll
            for (int ni = 0; ni < 4; ++ni) {
                float d = rsq + csq[ni] - 2.f * acc[mi][ni][reg];
                bool pos = (rt == ct[ni]);
                if (pos) { rap = fmaxf(rap, d); cap[ni] = fmaxf(cap[ni], d); }
                else     { ran = fminf(ran, d); can[ni] = fminf(can[ni], d); }
            }
            #pragma unroll
            for (int o = 1; o < 16; o <<= 1) {
                rap = fmaxf(rap, __shfl_xor(rap, o, 64));
                ran = fminf(ran, __shfl_xor(ran, o, 64));
            }
            rapv[mi * 4 + reg] = rap;
            ranv[mi * 4 + reg] = ran;
            if ((wave & 1) == 0 && fr == 0) {   // waves 0,2: deposit partials
                rowap[rl] = rap; rowan[rl] = ran;
            }
        }
    }

    // col partial: reduce across quads within wave
    #pragma unroll
    for (int ni = 0; ni < 4; ++ni) {
        #pragma unroll
        for (int o = 16; o < 64; o <<= 1) {
            cap[ni] = fmaxf(cap[ni], __shfl_xor(cap[ni], o, 64));
            can[ni] = fminf(can[ni], __shfl_xor(can[ni], o, 64));
        }
    }
    if (wave < 2 && lane < 16) {                // waves 0,1: deposit partials
        #pragma unroll
        for (int ni = 0; ni < 4; ++ni) {
            int c = wcol + ni * 16 + lane;
            colap[c] = cap[ni]; colan[c] = can[ni];
        }
    }

    __syncthreads();   // partials visible

    if (wave & 1) {                             // waves 1,3: finalize rows
        #pragma unroll
        for (int mi = 0; mi < 4; ++mi)
            #pragma unroll
            for (int reg = 0; reg < 4; ++reg) {
                int rl = wrow + mi * 16 + quad * 4 + reg;
                if (fr == 0) {
                    part_ap[(size_t)bx * B_N + bm + rl] =
                        fmaxf(rapv[mi * 4 + reg], rowap[rl]);
                    part_an[(size_t)bx * B_N + bm + rl] =
                        fminf(ranv[mi * 4 + reg], rowan[rl]);
                }
            }
    }
    if (wave >= 2 && bx != by && lane < 16) {   // waves 2,3: finalize cols
        #pragma unroll
        for (int ni = 0; ni < 4; ++ni) {
            int c = wcol + ni * 16 + lane;
            part_ap[(size_t)by * B_N + bn + c] = fmaxf(cap[ni], colap[c]);
            part_an[(size_t)by * B_N + bn + c] = fminf(can[ni], colan[c]);
        }
    }
}

// ---- kernel 3: reduce 64 partial slots/row + loss/prec + finalize ---------
__global__ __launch_bounds__(256) void final_kernel(
        const float* __restrict__ part_ap, const float* __restrict__ part_an,
        float* __restrict__ acc2, float* __restrict__ out) {
    __shared__ float s_sum[4], s_cnt[4];
    int i = blockIdx.x * 256 + threadIdx.x;     // 32 blocks x 256
    float ap = part_ap[i];
    float an = part_an[i];
    #pragma unroll 4
    for (int q = 1; q < NPAN; ++q) {
        ap = fmaxf(ap, part_ap[(size_t)q * B_N + i]);
        an = fminf(an, part_an[(size_t)q * B_N + i]);
    }
    float v  = ap - an + MARGIN;
    float sum = v > 0.f ? v : 0.f;
    float cnt = an > ap ? 1.f : 0.f;
    #pragma unroll
    for (int o = 32; o > 0; o >>= 1) {
        sum += __shfl_down(sum, o, 64);
        cnt += __shfl_down(cnt, o, 64);
    }
    int wave = threadIdx.x >> 6, lane = threadIdx.x & 63;
    if (lane == 0) { s_sum[wave] = sum; s_cnt[wave] = cnt; }
    __syncthreads();
    if (threadIdx.x == 0) {
        float ts = 0.f, tc = 0.f;
        #pragma unroll
        for (int w = 0; w < 4; ++w) { ts += s_sum[w]; tc += s_cnt[w]; }
        atomicAdd(&acc2[0], ts);
        atomicAdd(&acc2[1], tc);
        __threadfence();
        unsigned ticket = atomicAdd(reinterpret_cast<unsigned*>(acc2) + 2, 1u);
        if (ticket == gridDim.x - 1) {
            float fs = atomicAdd(&acc2[0], 0.f);
            float fc = atomicAdd(&acc2[1], 0.f);
            out[0] = fs / (float)B_N;
            out[1] = fc / (float)B_N;
        }
    }
}

extern "C" void kernel_launch(void* const* d_in, const int* in_sizes, int n_in,
                              void* d_out, int out_size, void* d_ws, size_t ws_size,
                              hipStream_t stream) {
    const float* X   = (const float*)d_in[0];
    const int*   tgt = (const int*)d_in[1];

    char* ws = (char*)d_ws;
    float*          sq      = (float*)ws;                        // 32 KB
    float*          acc2    = (float*)(ws + 32768);              // 16 B
    float*          part_ap = (float*)(ws + 65536);              // 2 MB
    float*          part_an = (float*)(ws + 65536 + 2097152);    // 2 MB
    unsigned short* Xp      = (unsigned short*)(ws + 65536 + 4194304); // 4 MB

    float* out = (float*)d_out;

    prep_kernel<<<B_N / 4, 256, 0, stream>>>(X, sq, Xp, acc2);
    dist_kernel<<<(64 * 65) / 2, 256, 0, stream>>>(Xp, tgt, sq, part_ap, part_an);
    final_kernel<<<B_N / 256, 256, 0, stream>>>(part_ap, part_an, acc2, out);
}